// Round 2
// baseline (1217.032 us; speedup 1.0000x reference)
//
#include <hip/hip_runtime.h>

using u16 = unsigned short;
using u32 = unsigned int;

typedef short s16x8 __attribute__((ext_vector_type(8)));
typedef float f32x4 __attribute__((ext_vector_type(4)));

#define DEV static __device__ __forceinline__
#define AS1 __attribute__((address_space(1)))
#define AS3 __attribute__((address_space(3)))

DEV u16 f2bf(float f){
  u32 u = __float_as_uint(f);
  return (u16)((u + 0x7fffu + ((u >> 16) & 1u)) >> 16);
}
DEV float bf2f(u16 h){ return __uint_as_float(((u32)h) << 16); }

DEV void gload_lds16(const u16* g, u16* l){
  __builtin_amdgcn_global_load_lds((const AS1 void*)g, (AS3 void*)l, 16, 0, 0);
}

// ------------------------------------------------------------------
// weight cast fp32 -> bf16, 6 segments packed contiguously
// ------------------------------------------------------------------
__global__ __launch_bounds__(256) void cast_w(
    const float* __restrict__ s0, const float* __restrict__ s1,
    const float* __restrict__ s2, const float* __restrict__ s3,
    const float* __restrict__ s4, const float* __restrict__ s5,
    u16* __restrict__ dst)
{
  size_t base = ((size_t)blockIdx.x * 256 + threadIdx.x) * 4;
  if (base >= 15007744u) return;
  const float* src; size_t off;
  if      (base <  4194304u){ src=s0; off=base;           }
  else if (base <  4390912u){ src=s1; off=base- 4194304u; }
  else if (base <  4521984u){ src=s2; off=base- 4390912u; }
  else if (base <  6619136u){ src=s3; off=base- 4521984u; }
  else if (base < 10813440u){ src=s4; off=base- 6619136u; }
  else                      { src=s5; off=base-10813440u; }
  float4 v = *(const float4*)(src + off);
  *(ushort4*)(dst + base) = make_ushort4(f2bf(v.x), f2bf(v.y), f2bf(v.z), f2bf(v.w));
}

// ------------------------------------------------------------------
// layernorm over 1024, output bf16. one block per row.
// ------------------------------------------------------------------
__global__ __launch_bounds__(256) void ln_bf16(
    const float* __restrict__ x, const float* __restrict__ g,
    const float* __restrict__ b, u16* __restrict__ o)
{
  int row = blockIdx.x, t = threadIdx.x;
  float4 v = ((const float4*)(x + (size_t)row*1024))[t];
  float s  = v.x+v.y+v.z+v.w;
  float ss = v.x*v.x+v.y*v.y+v.z*v.z+v.w*v.w;
  #pragma unroll
  for (int off=32; off; off>>=1){ s += __shfl_down(s,off); ss += __shfl_down(ss,off); }
  __shared__ float red[8];
  int lane = t & 63, w = t >> 6;
  if (lane==0){ red[w]=s; red[4+w]=ss; }
  __syncthreads();
  float S  = red[0]+red[1]+red[2]+red[3];
  float SS = red[4]+red[5]+red[6]+red[7];
  float mu = S * (1.f/1024.f);
  float var = SS * (1.f/1024.f) - mu*mu;
  float rs = rsqrtf(var + 1e-5f);
  float4 gg = ((const float4*)g)[t], bb = ((const float4*)b)[t];
  ((ushort4*)o)[(size_t)row*256 + t] = make_ushort4(
    f2bf((v.x-mu)*rs*gg.x + bb.x), f2bf((v.y-mu)*rs*gg.y + bb.y),
    f2bf((v.z-mu)*rs*gg.z + bb.z), f2bf((v.w-mu)*rs*gg.w + bb.w));
}

// ------------------------------------------------------------------
// causal depthwise conv (D_CONV=4) + bias + silu, bf16 in -> bf16 out
// thread handles 4 consecutive channels; ushort4 loads.
// ------------------------------------------------------------------
__global__ __launch_bounds__(256) void conv_silu(
    const u16* __restrict__ xi, const float* __restrict__ cw,
    const float* __restrict__ cb, u16* __restrict__ ob)
{
  int idx = blockIdx.x*256 + threadIdx.x;   // 4,194,304 threads
  int d4 = (idx & 511) << 2;
  int l  = (idx >> 9) & 2047;
  int b  = idx >> 20;
  float4 w0 = ((const float4*)cw)[d4+0];
  float4 w1 = ((const float4*)cw)[d4+1];
  float4 w2 = ((const float4*)cw)[d4+2];
  float4 w3 = ((const float4*)cw)[d4+3];
  float4 bb = *(const float4*)(cb + d4);
  float a0=bb.x, a1=bb.y, a2=bb.z, a3=bb.w;
  size_t rowbase = ((size_t)b*2048 + l)*2048 + d4;
  #pragma unroll
  for (int j=0;j<4;j++){
    int ls = l - 3 + j;
    if (ls >= 0){
      ushort4 xv = *(const ushort4*)(xi + rowbase + (size_t)(j-3)*2048);
      a0 += (&w0.x)[j]*bf2f(xv.x);
      a1 += (&w1.x)[j]*bf2f(xv.y);
      a2 += (&w2.x)[j]*bf2f(xv.z);
      a3 += (&w3.x)[j]*bf2f(xv.w);
    }
  }
  ushort4 o;
  o.x = f2bf(a0/(1.f+__expf(-a0)));
  o.y = f2bf(a1/(1.f+__expf(-a1)));
  o.z = f2bf(a2/(1.f+__expf(-a2)));
  o.w = f2bf(a3/(1.f+__expf(-a3)));
  *(ushort4*)(ob + rowbase) = o;
}

// ------------------------------------------------------------------
// reduce 4 K-split partials of x_dbl [8192,96]; also emit dt_raw bf16
// ------------------------------------------------------------------
__global__ __launch_bounds__(256) void xred(
    const float* __restrict__ xp, float* __restrict__ xd, u16* __restrict__ dr)
{
  int i = blockIdx.x*256 + threadIdx.x;   // 786432
  float v = xp[i] + xp[786432 + i] + xp[2*786432 + i] + xp[3*786432 + i];
  xd[i] = v;
  int row = i / 96, col = i - row*96;
  if (col < 64) dr[(size_t)row*64 + col] = f2bf(v);
}

// ------------------------------------------------------------------
// SSM scan: thread per (b,d,n). grid (128,4), block 256 = 16 d x 16 n.
// LDS-chunked staging of 32 timesteps. Fused y=(y+Dp*u)*silu(z) -> bf16
// ------------------------------------------------------------------
__global__ __launch_bounds__(256) void ssm_scan(
    const u16* __restrict__ dt, const float* __restrict__ xdbl,
    const u16* __restrict__ u, const u16* __restrict__ zb,
    const float* __restrict__ alog, const float* __restrict__ dp,
    u16* __restrict__ yg)
{
  int b = blockIdx.y, d0 = blockIdx.x * 16;
  int t = threadIdx.x, dl = t >> 4, n = t & 15;
  int d = d0 + dl;
  float An  = -__expf(alog[(size_t)d*16 + n]);
  float Dpd = dp[d];
  float h = 0.f;
  __shared__ u16 sdt[32][16], su[32][16], sz[32][16];
  __shared__ float sBC[32][32];
  for (int l0 = 0; l0 < 2048; l0 += 32){
    __syncthreads();
    {
      int r = t >> 4, c = t & 15;
      #pragma unroll
      for (int rr = 0; rr < 2; rr++){
        int row = r + rr*16;
        size_t gi = ((size_t)b*2048 + l0 + row)*2048 + d0 + c;
        sdt[row][c] = dt[gi];
        su[row][c]  = u[gi];
        sz[row][c]  = zb[gi];
      }
      int r2 = t >> 5, c2 = t & 31;
      #pragma unroll
      for (int rr = 0; rr < 4; rr++){
        int row = r2 + rr*8;
        sBC[row][c2] = xdbl[((size_t)b*2048 + l0 + row)*96 + 64 + c2];
      }
    }
    __syncthreads();
    #pragma unroll 4
    for (int l = 0; l < 32; l++){
      float dtv = bf2f(sdt[l][dl]);
      float uv  = bf2f(su[l][dl]);
      float dA = __expf(dtv * An);
      h = dA*h + dtv*uv*sBC[l][n];
      float p = h * sBC[l][16+n];
      p += __shfl_xor(p, 1);
      p += __shfl_xor(p, 2);
      p += __shfl_xor(p, 4);
      p += __shfl_xor(p, 8);
      if (n == 0){
        float zv = bf2f(sz[l][dl]);
        float yv = (p + Dpd*uv) * (zv / (1.f + __expf(-zv)));
        yg[((size_t)b*2048 + l0 + l)*2048 + d] = f2bf(yv);
      }
    }
  }
}

// ------------------------------------------------------------------
// generic bf16 GEMM: out[M,N] = A[M,K] @ W[N,K]^T  (both K-contiguous)
// 128x128 tile, BK=32, 4 waves x (4x4) 16x16x32 MFMA fragments.
// EPI: 0 split xi bf16 | z bf16
//      1 K-split partial f32 (slice blockIdx.z, width Nreal)
//      2 softplus(v+bias) -> bf16
//      3 v + resid  -> f32
//      4 bias+relu  -> bf16
//      5 v + bias + resid -> f32 (same-thread RMW ok when F0==C1)
// ------------------------------------------------------------------
template<int EPI>
__global__ __launch_bounds__(256) void gemm_bt(
    const u16* __restrict__ A, const u16* __restrict__ W,
    int M, int N, int K, int Nreal,
    float* __restrict__ F0, const float* __restrict__ C0,
    const float* __restrict__ C1, u16* __restrict__ OB, u16* __restrict__ OB2)
{
  __shared__ __attribute__((aligned(16))) u16 sA[128*32];
  __shared__ __attribute__((aligned(16))) u16 sB[128*32];
  const int tid  = threadIdx.x;
  const int lane = tid & 63;
  const int wid  = tid >> 6;
  const int wr = wid >> 1, wc = wid & 1;
  const int bm = blockIdx.y * 128, bn = blockIdx.x * 128;

  const int kchunk = K / (int)gridDim.z;
  const int k0 = (int)blockIdx.z * kchunk, k1 = k0 + kchunk;

  f32x4 acc[4][4];
  #pragma unroll
  for (int m=0;m<4;m++)
    #pragma unroll
    for (int nn=0;nn<4;nn++) acc[m][nn] = (f32x4){0.f,0.f,0.f,0.f};

  const int c0 = tid,        r0a = c0 >> 2, cc0 = c0 & 3;
  const int c1 = tid + 256,  r1a = c1 >> 2, cc1 = c1 & 3;
  int wrow0 = bn + r0a; if (wrow0 > Nreal-1) wrow0 = Nreal-1;
  int wrow1 = bn + r1a; if (wrow1 > Nreal-1) wrow1 = Nreal-1;

  const int frow = lane & 15;
  const int ksel = lane >> 4;

  for (int kt = k0; kt < k1; kt += 32){
    gload_lds16(A + (size_t)(bm + r0a)*K + kt + cc0*8, &sA[c0*8]);
    gload_lds16(A + (size_t)(bm + r1a)*K + kt + cc1*8, &sA[c1*8]);
    gload_lds16(W + (size_t)wrow0*K + kt + cc0*8, &sB[c0*8]);
    gload_lds16(W + (size_t)wrow1*K + kt + cc1*8, &sB[c1*8]);
    __syncthreads();
    s16x8 af[4], bfr[4];
    #pragma unroll
    for (int m=0;m<4;m++)
      af[m] = *(const s16x8*)&sA[(wr*64 + m*16 + frow)*32 + ksel*8];
    #pragma unroll
    for (int nn=0;nn<4;nn++)
      bfr[nn] = *(const s16x8*)&sB[(wc*64 + nn*16 + frow)*32 + ksel*8];
    #pragma unroll
    for (int m=0;m<4;m++)
      #pragma unroll
      for (int nn=0;nn<4;nn++)
        acc[m][nn] = __builtin_amdgcn_mfma_f32_16x16x32_bf16(af[m], bfr[nn], acc[m][nn], 0, 0, 0);
    __syncthreads();
  }

  const int crow0 = (lane >> 4) * 4;
  const int ccol  = lane & 15;
  #pragma unroll
  for (int m=0;m<4;m++){
    #pragma unroll
    for (int nn=0;nn<4;nn++){
      #pragma unroll
      for (int j=0;j<4;j++){
        int grow = bm + wr*64 + m*16 + crow0 + j;
        int gcol = bn + wc*64 + nn*16 + ccol;
        float v = acc[m][nn][j];
        if constexpr (EPI==0){            // split: xi bf16 | z bf16
          if (gcol < 2048) OB2[(size_t)grow*2048 + gcol] = f2bf(v);
          else             OB[(size_t)grow*2048 + (gcol-2048)] = f2bf(v);
        } else if constexpr (EPI==1){     // K-split partial slice
          if (gcol < Nreal)
            F0[((size_t)blockIdx.z*M + grow)*Nreal + gcol] = v;
        } else if constexpr (EPI==2){     // softplus(v + bias) -> bf16
          v += C0[gcol];
          v = (v > 20.f) ? v : log1pf(__expf(v));
          OB[(size_t)grow*N + gcol] = f2bf(v);
        } else if constexpr (EPI==3){     // + residual -> f32
          F0[(size_t)grow*N + gcol] = v + C1[(size_t)grow*N + gcol];
        } else if constexpr (EPI==4){     // bias + relu -> bf16
          v += C0[gcol]; v = fmaxf(v, 0.f);
          OB[(size_t)grow*N + gcol] = f2bf(v);
        } else {                          // 5: bias + residual -> f32
          F0[(size_t)grow*N + gcol] = v + C0[gcol] + C1[(size_t)grow*N + gcol];
        }
      }
    }
  }
}

// ------------------------------------------------------------------
extern "C" void kernel_launch(void* const* d_in, const int* in_sizes, int n_in,
                              void* d_out, int out_size, void* d_ws, size_t ws_size,
                              hipStream_t stream)
{
  const float* X    = (const float*)d_in[0];
  const float* LN1G = (const float*)d_in[1];
  const float* LN1B = (const float*)d_in[2];
  const float* LN2G = (const float*)d_in[3];
  const float* LN2B = (const float*)d_in[4];
  const float* INW  = (const float*)d_in[5];
  const float* CONVW= (const float*)d_in[6];
  const float* CONVB= (const float*)d_in[7];
  const float* XPW  = (const float*)d_in[8];
  const float* DTW  = (const float*)d_in[9];
  const float* DTBIA= (const float*)d_in[10];
  const float* ALOG = (const float*)d_in[11];
  const float* DP   = (const float*)d_in[12];
  const float* OUTW = (const float*)d_in[13];
  const float* W1   = (const float*)d_in[14];
  const float* B1   = (const float*)d_in[15];
  const float* W2   = (const float*)d_in[16];
  const float* B2   = (const float*)d_in[17];

  char* ws = (char*)d_ws;
  // bf16 weight pack (u16 element offsets)
  u16* WB   = (u16*)ws;
  u16* bIN  = WB;              // [4096,1024]
  u16* bXP  = WB + 4194304;    // [96,2048]
  u16* bDT  = WB + 4390912;    // [2048,64]
  u16* bOUT = WB + 4521984;    // [1024,2048]
  u16* bW1  = WB + 6619136;    // [4096,1024]
  u16* bW2  = WB + 10813440;   // [1024,4096]
  // activations (byte offsets; overlapped per liveness timeline)
  u16*   H1    = (u16*)(ws + 30015488);    // ln out bf16 (h1, later h2)
  u16*   ZB    = (u16*)(ws + 46792704);    // z bf16 [8192,2048]
  u16*   XIPRE = (u16*)(ws + 80347136);    // xi pre-conv bf16; later YG
  u16*   YG    = XIPRE;
  u16*   XIB   = (u16*)(ws + 113901568);   // u = silu(conv) bf16
  u16*   DTQ   = (u16*)(ws + 147456000);   // dt bf16 [8192,2048]
  float* XPART = (float*)(ws + 181010432); // 4 x [8192,96] f32 partials
  float* XDBL  = (float*)(ws + 193593344); // [8192,96] f32
  u16*   DTRAW = (u16*)(ws + 196739072);   // [8192,64] bf16
  u16*   F1    = ZB;                       // ffn hidden bf16 [8192,4096] (ZB+YG dead)
  float* X2    = (float*)d_out;            // residual stream lives in d_out

  cast_w<<<14656, 256, 0, stream>>>(INW, XPW, DTW, OUTW, W1, W2, WB);
  ln_bf16<<<8192, 256, 0, stream>>>(X, LN1G, LN1B, H1);
  // in_proj: [8192,1024] x [4096,1024]^T -> xi bf16 | z bf16
  gemm_bt<0><<<dim3(32,64,1), 256, 0, stream>>>(H1, bIN, 8192, 4096, 1024, 4096,
                                                nullptr, nullptr, nullptr, ZB, XIPRE);
  conv_silu<<<16384, 256, 0, stream>>>(XIPRE, CONVW, CONVB, XIB);
  // x_proj: [8192,2048] x [96,2048]^T, N padded to 128, K-split 4 -> partials
  gemm_bt<1><<<dim3(1,64,4), 256, 0, stream>>>(XIB, bXP, 8192, 128, 2048, 96,
                                               XPART, nullptr, nullptr, nullptr, nullptr);
  xred<<<3072, 256, 0, stream>>>(XPART, XDBL, DTRAW);
  // dt_proj: [8192,64] x [2048,64]^T, + bias, softplus -> bf16
  gemm_bt<2><<<dim3(16,64,1), 256, 0, stream>>>(DTRAW, bDT, 8192, 2048, 64, 2048,
                                                nullptr, DTBIA, nullptr, DTQ, nullptr);
  ssm_scan<<<dim3(128,4,1), 256, 0, stream>>>(DTQ, XDBL, XIB, ZB, ALOG, DP, YG);
  // out_proj + residual(x) -> X2 (= d_out region, overwritten later only by EPI5 RMW)
  gemm_bt<3><<<dim3(8,64,1), 256, 0, stream>>>(YG, bOUT, 8192, 1024, 2048, 1024,
                                               X2, nullptr, X, nullptr, nullptr);
  ln_bf16<<<8192, 256, 0, stream>>>(X2, LN2G, LN2B, H1);
  // ffn1 + bias + relu -> bf16
  gemm_bt<4><<<dim3(32,64,1), 256, 0, stream>>>(H1, bW1, 8192, 4096, 1024, 4096,
                                                nullptr, B1, nullptr, F1, nullptr);
  // ffn2 + bias + residual(X2) -> d_out (F0==C1, same-thread RMW)
  gemm_bt<5><<<dim3(8,64,1), 256, 0, stream>>>(F1, bW2, 8192, 1024, 4096, 1024,
                                               (float*)d_out, B2, X2, nullptr, nullptr);
}

// Round 3
// 799.757 us; speedup vs baseline: 1.5218x; 1.5218x over previous
//
#include <hip/hip_runtime.h>

using u16 = unsigned short;
using u32 = unsigned int;

typedef short s16x8 __attribute__((ext_vector_type(8)));
typedef float f32x4 __attribute__((ext_vector_type(4)));

#define DEV static __device__ __forceinline__
#define AS1 __attribute__((address_space(1)))
#define AS3 __attribute__((address_space(3)))

DEV u16 f2bf(float f){
  u32 u = __float_as_uint(f);
  return (u16)((u + 0x7fffu + ((u >> 16) & 1u)) >> 16);
}
DEV float bf2f(u16 h){ return __uint_as_float(((u32)h) << 16); }

DEV void gload_lds16(const u16* g, u16* l){
  __builtin_amdgcn_global_load_lds((const AS1 void*)g, (AS3 void*)l, 16, 0, 0);
}

// ------------------------------------------------------------------
// weight cast fp32 -> bf16, 6 segments packed contiguously
// ------------------------------------------------------------------
__global__ __launch_bounds__(256) void cast_w(
    const float* __restrict__ s0, const float* __restrict__ s1,
    const float* __restrict__ s2, const float* __restrict__ s3,
    const float* __restrict__ s4, const float* __restrict__ s5,
    u16* __restrict__ dst)
{
  size_t base = ((size_t)blockIdx.x * 256 + threadIdx.x) * 4;
  if (base >= 15007744u) return;
  const float* src; size_t off;
  if      (base <  4194304u){ src=s0; off=base;           }
  else if (base <  4390912u){ src=s1; off=base- 4194304u; }
  else if (base <  4521984u){ src=s2; off=base- 4390912u; }
  else if (base <  6619136u){ src=s3; off=base- 4521984u; }
  else if (base < 10813440u){ src=s4; off=base- 6619136u; }
  else                      { src=s5; off=base-10813440u; }
  float4 v = *(const float4*)(src + off);
  *(ushort4*)(dst + base) = make_ushort4(f2bf(v.x), f2bf(v.y), f2bf(v.z), f2bf(v.w));
}

// ------------------------------------------------------------------
// layernorm over 1024, output bf16. one block per row.
// ------------------------------------------------------------------
__global__ __launch_bounds__(256) void ln_bf16(
    const float* __restrict__ x, const float* __restrict__ g,
    const float* __restrict__ b, u16* __restrict__ o)
{
  int row = blockIdx.x, t = threadIdx.x;
  float4 v = ((const float4*)(x + (size_t)row*1024))[t];
  float s  = v.x+v.y+v.z+v.w;
  float ss = v.x*v.x+v.y*v.y+v.z*v.z+v.w*v.w;
  #pragma unroll
  for (int off=32; off; off>>=1){ s += __shfl_down(s,off); ss += __shfl_down(ss,off); }
  __shared__ float red[8];
  int lane = t & 63, w = t >> 6;
  if (lane==0){ red[w]=s; red[4+w]=ss; }
  __syncthreads();
  float S  = red[0]+red[1]+red[2]+red[3];
  float SS = red[4]+red[5]+red[6]+red[7];
  float mu = S * (1.f/1024.f);
  float var = SS * (1.f/1024.f) - mu*mu;
  float rs = rsqrtf(var + 1e-5f);
  float4 gg = ((const float4*)g)[t], bb = ((const float4*)b)[t];
  ((ushort4*)o)[(size_t)row*256 + t] = make_ushort4(
    f2bf((v.x-mu)*rs*gg.x + bb.x), f2bf((v.y-mu)*rs*gg.y + bb.y),
    f2bf((v.z-mu)*rs*gg.z + bb.z), f2bf((v.w-mu)*rs*gg.w + bb.w));
}

// ------------------------------------------------------------------
// causal depthwise conv (D_CONV=4) + bias + silu, bf16 in -> bf16 out
// ------------------------------------------------------------------
__global__ __launch_bounds__(256) void conv_silu(
    const u16* __restrict__ xi, const float* __restrict__ cw,
    const float* __restrict__ cb, u16* __restrict__ ob)
{
  int idx = blockIdx.x*256 + threadIdx.x;   // 4,194,304 threads
  int d4 = (idx & 511) << 2;
  int l  = (idx >> 9) & 2047;
  int b  = idx >> 20;
  float4 w0 = ((const float4*)cw)[d4+0];
  float4 w1 = ((const float4*)cw)[d4+1];
  float4 w2 = ((const float4*)cw)[d4+2];
  float4 w3 = ((const float4*)cw)[d4+3];
  float4 bb = *(const float4*)(cb + d4);
  float a0=bb.x, a1=bb.y, a2=bb.z, a3=bb.w;
  size_t rowbase = ((size_t)b*2048 + l)*2048 + d4;
  #pragma unroll
  for (int j=0;j<4;j++){
    int ls = l - 3 + j;
    if (ls >= 0){
      ushort4 xv = *(const ushort4*)(xi + rowbase + (size_t)(j-3)*2048);
      a0 += (&w0.x)[j]*bf2f(xv.x);
      a1 += (&w1.x)[j]*bf2f(xv.y);
      a2 += (&w2.x)[j]*bf2f(xv.z);
      a3 += (&w3.x)[j]*bf2f(xv.w);
    }
  }
  ushort4 o;
  o.x = f2bf(a0/(1.f+__expf(-a0)));
  o.y = f2bf(a1/(1.f+__expf(-a1)));
  o.z = f2bf(a2/(1.f+__expf(-a2)));
  o.w = f2bf(a3/(1.f+__expf(-a3)));
  *(ushort4*)(ob + rowbase) = o;
}

// ------------------------------------------------------------------
// reduce 4 K-split partials of x_dbl [8192,96]; also emit dt_raw bf16
// ------------------------------------------------------------------
__global__ __launch_bounds__(256) void xred(
    const float* __restrict__ xp, float* __restrict__ xd, u16* __restrict__ dr)
{
  int i = blockIdx.x*256 + threadIdx.x;   // 786432
  float v = xp[i] + xp[786432 + i] + xp[2*786432 + i] + xp[3*786432 + i];
  xd[i] = v;
  int row = i / 96, col = i - row*96;
  if (col < 64) dr[(size_t)row*64 + col] = f2bf(v);
}

// ==================================================================
// Chunked SSM scan. L=2048 split into S=32 chunks of 64 steps.
// Recurrence h_t = exp(dt_t*A)h_{t-1} + dt_t*u_t*B_t is linear;
// cross-chunk propagator = exp(A * sum(dt)) over the chunk.
// ==================================================================

// pass A: per (d-group, b, chunk): local scan from h=0, 16 n-states in
// registers. Emits h_end[16] and sum(dt).
__global__ __launch_bounds__(256) void scan_a(
    const u16* __restrict__ dtq, const u16* __restrict__ u,
    const float* __restrict__ xdbl, const float* __restrict__ alog,
    float* __restrict__ hend, float* __restrict__ sdt)
{
  int d = blockIdx.x*256 + threadIdx.x;
  int b = blockIdx.y, s = blockIdx.z, l0 = s*64;
  __shared__ float sB[64][16];
  for (int i = threadIdx.x; i < 1024; i += 256){
    int row = i >> 4, c = i & 15;
    sB[row][c] = xdbl[((size_t)(b*2048 + l0 + row))*96 + 64 + c];
  }
  float afn[16];
  #pragma unroll
  for (int n=0;n<16;n++) afn[n] = -__expf(alog[d*16+n]);
  __syncthreads();
  float h[16];
  #pragma unroll
  for (int n=0;n<16;n++) h[n] = 0.f;
  float sum_dt = 0.f;
  size_t base = ((size_t)b*2048 + l0)*2048 + d;
  for (int t=0;t<64;t++){
    float dtv = bf2f(dtq[base]);
    float uv  = bf2f(u[base]);
    sum_dt += dtv;
    float dtu = dtv*uv;
    #pragma unroll
    for (int n=0;n<16;n++)
      h[n] = __expf(dtv*afn[n])*h[n] + dtu*sB[t][n];
    base += 2048;
  }
  sdt[(b*32+s)*2048 + d] = sum_dt;
  size_t hb = ((size_t)(b*32+s)*16)*2048 + d;
  #pragma unroll
  for (int n=0;n<16;n++) hend[hb + (size_t)n*2048] = h[n];
}

// pass B: thread per (b,d,n): sequential over 32 chunks, converts
// hend -> hstart IN PLACE. h_start(0)=0; h_start(s+1)=hend(s)+h_start(s)*P(s)
__global__ __launch_bounds__(256) void scan_b(
    float* __restrict__ hend, const float* __restrict__ sdt,
    const float* __restrict__ alog)
{
  int g = blockIdx.x*256 + threadIdx.x;  // 131072
  int d = g & 2047, n = (g >> 11) & 15, b = g >> 15;
  float An = -__expf(alog[d*16+n]);
  float h = 0.f;
  for (int s=0;s<32;s++){
    size_t hi = ((size_t)((b*32+s)*16) + n)*2048 + d;
    float he = hend[hi];
    hend[hi] = h;
    h = he + h*__expf(An * sdt[(b*32+s)*2048 + d]);
  }
}

// pass C: re-run chunk from correct h_start; fused y=(y+Dp*u)*silu(z)->bf16
__global__ __launch_bounds__(256) void scan_c(
    const u16* __restrict__ dtq, const u16* __restrict__ u,
    const u16* __restrict__ zb, const float* __restrict__ xdbl,
    const float* __restrict__ alog, const float* __restrict__ dp,
    const float* __restrict__ hstart, u16* __restrict__ yg)
{
  int d = blockIdx.x*256 + threadIdx.x;
  int b = blockIdx.y, s = blockIdx.z, l0 = s*64;
  __shared__ float sB[64][16], sC[64][16];
  for (int i = threadIdx.x; i < 1024; i += 256){
    int row = i >> 4, c = i & 15;
    size_t xb = ((size_t)(b*2048 + l0 + row))*96 + 64;
    sB[row][c] = xdbl[xb + c];
    sC[row][c] = xdbl[xb + 16 + c];
  }
  float afn[16];
  #pragma unroll
  for (int n=0;n<16;n++) afn[n] = -__expf(alog[d*16+n]);
  __syncthreads();
  float h[16];
  size_t hb = ((size_t)((b*32+s)*16))*2048 + d;
  #pragma unroll
  for (int n=0;n<16;n++) h[n] = hstart[hb + (size_t)n*2048];
  float Dpd = dp[d];
  size_t base = ((size_t)b*2048 + l0)*2048 + d;
  for (int t=0;t<64;t++){
    float dtv = bf2f(dtq[base]);
    float uv  = bf2f(u[base]);
    float dtu = dtv*uv;
    float y = 0.f;
    #pragma unroll
    for (int n=0;n<16;n++){
      h[n] = __expf(dtv*afn[n])*h[n] + dtu*sB[t][n];
      y += h[n]*sC[t][n];
    }
    float zv = bf2f(zb[base]);
    float yv = (y + Dpd*uv) * (zv / (1.f + __expf(-zv)));
    yg[base] = f2bf(yv);
    base += 2048;
  }
}

// ------------------------------------------------------------------
// generic bf16 GEMM: out[M,N] = A[M,K] @ W[N,K]^T  (both K-contiguous)
// 128x128 tile, BK=32, 4 waves x (4x4) 16x16x32 MFMA fragments.
// ------------------------------------------------------------------
template<int EPI>
__global__ __launch_bounds__(256) void gemm_bt(
    const u16* __restrict__ A, const u16* __restrict__ W,
    int M, int N, int K, int Nreal,
    float* __restrict__ F0, const float* __restrict__ C0,
    const float* __restrict__ C1, u16* __restrict__ OB, u16* __restrict__ OB2)
{
  __shared__ __attribute__((aligned(16))) u16 sA[128*32];
  __shared__ __attribute__((aligned(16))) u16 sB[128*32];
  const int tid  = threadIdx.x;
  const int lane = tid & 63;
  const int wid  = tid >> 6;
  const int wr = wid >> 1, wc = wid & 1;
  const int bm = blockIdx.y * 128, bn = blockIdx.x * 128;

  const int kchunk = K / (int)gridDim.z;
  const int k0 = (int)blockIdx.z * kchunk, k1 = k0 + kchunk;

  f32x4 acc[4][4];
  #pragma unroll
  for (int m=0;m<4;m++)
    #pragma unroll
    for (int nn=0;nn<4;nn++) acc[m][nn] = (f32x4){0.f,0.f,0.f,0.f};

  const int c0 = tid,        r0a = c0 >> 2, cc0 = c0 & 3;
  const int c1 = tid + 256,  r1a = c1 >> 2, cc1 = c1 & 3;
  int wrow0 = bn + r0a; if (wrow0 > Nreal-1) wrow0 = Nreal-1;
  int wrow1 = bn + r1a; if (wrow1 > Nreal-1) wrow1 = Nreal-1;

  const int frow = lane & 15;
  const int ksel = lane >> 4;

  for (int kt = k0; kt < k1; kt += 32){
    gload_lds16(A + (size_t)(bm + r0a)*K + kt + cc0*8, &sA[c0*8]);
    gload_lds16(A + (size_t)(bm + r1a)*K + kt + cc1*8, &sA[c1*8]);
    gload_lds16(W + (size_t)wrow0*K + kt + cc0*8, &sB[c0*8]);
    gload_lds16(W + (size_t)wrow1*K + kt + cc1*8, &sB[c1*8]);
    __syncthreads();
    s16x8 af[4], bfr[4];
    #pragma unroll
    for (int m=0;m<4;m++)
      af[m] = *(const s16x8*)&sA[(wr*64 + m*16 + frow)*32 + ksel*8];
    #pragma unroll
    for (int nn=0;nn<4;nn++)
      bfr[nn] = *(const s16x8*)&sB[(wc*64 + nn*16 + frow)*32 + ksel*8];
    #pragma unroll
    for (int m=0;m<4;m++)
      #pragma unroll
      for (int nn=0;nn<4;nn++)
        acc[m][nn] = __builtin_amdgcn_mfma_f32_16x16x32_bf16(af[m], bfr[nn], acc[m][nn], 0, 0, 0);
    __syncthreads();
  }

  const int crow0 = (lane >> 4) * 4;
  const int ccol  = lane & 15;
  #pragma unroll
  for (int m=0;m<4;m++){
    #pragma unroll
    for (int nn=0;nn<4;nn++){
      #pragma unroll
      for (int j=0;j<4;j++){
        int grow = bm + wr*64 + m*16 + crow0 + j;
        int gcol = bn + wc*64 + nn*16 + ccol;
        float v = acc[m][nn][j];
        if constexpr (EPI==0){            // split: xi bf16 | z bf16
          if (gcol < 2048) OB2[(size_t)grow*2048 + gcol] = f2bf(v);
          else             OB[(size_t)grow*2048 + (gcol-2048)] = f2bf(v);
        } else if constexpr (EPI==1){     // K-split partial slice
          if (gcol < Nreal)
            F0[((size_t)blockIdx.z*M + grow)*Nreal + gcol] = v;
        } else if constexpr (EPI==2){     // softplus(v + bias) -> bf16
          v += C0[gcol];
          v = (v > 20.f) ? v : log1pf(__expf(v));
          OB[(size_t)grow*N + gcol] = f2bf(v);
        } else if constexpr (EPI==3){     // + residual -> f32
          F0[(size_t)grow*N + gcol] = v + C1[(size_t)grow*N + gcol];
        } else if constexpr (EPI==4){     // bias + relu -> bf16
          v += C0[gcol]; v = fmaxf(v, 0.f);
          OB[(size_t)grow*N + gcol] = f2bf(v);
        } else {                          // 5: bias + residual -> f32
          F0[(size_t)grow*N + gcol] = v + C0[gcol] + C1[(size_t)grow*N + gcol];
        }
      }
    }
  }
}

// ------------------------------------------------------------------
extern "C" void kernel_launch(void* const* d_in, const int* in_sizes, int n_in,
                              void* d_out, int out_size, void* d_ws, size_t ws_size,
                              hipStream_t stream)
{
  const float* X    = (const float*)d_in[0];
  const float* LN1G = (const float*)d_in[1];
  const float* LN1B = (const float*)d_in[2];
  const float* LN2G = (const float*)d_in[3];
  const float* LN2B = (const float*)d_in[4];
  const float* INW  = (const float*)d_in[5];
  const float* CONVW= (const float*)d_in[6];
  const float* CONVB= (const float*)d_in[7];
  const float* XPW  = (const float*)d_in[8];
  const float* DTW  = (const float*)d_in[9];
  const float* DTBIA= (const float*)d_in[10];
  const float* ALOG = (const float*)d_in[11];
  const float* DP   = (const float*)d_in[12];
  const float* OUTW = (const float*)d_in[13];
  const float* W1   = (const float*)d_in[14];
  const float* B1   = (const float*)d_in[15];
  const float* W2   = (const float*)d_in[16];
  const float* B2   = (const float*)d_in[17];

  char* ws = (char*)d_ws;
  // bf16 weight pack (u16 element offsets)
  u16* WB   = (u16*)ws;
  u16* bIN  = WB;              // [4096,1024]
  u16* bXP  = WB + 4194304;    // [96,2048]
  u16* bDT  = WB + 4390912;    // [2048,64]
  u16* bOUT = WB + 4521984;    // [1024,2048]
  u16* bW1  = WB + 6619136;    // [4096,1024]
  u16* bW2  = WB + 10813440;   // [1024,4096]
  // activations (byte offsets; overlapped per liveness timeline)
  u16*   H1    = (u16*)(ws + 30015488);    // ln out bf16 (h1, later h2)
  float* HEND  = (float*)(ws + 30015488);  // scan h_end/h_start [4][32][16][2048] f32
                                           // (reuses H1: dead between in_proj and ln2)
  u16*   ZB    = (u16*)(ws + 46792704);    // z bf16 [8192,2048]
  u16*   XIPRE = (u16*)(ws + 80347136);    // xi pre-conv bf16; later YG
  u16*   YG    = XIPRE;
  u16*   XIB   = (u16*)(ws + 113901568);   // u = silu(conv) bf16
  u16*   DTQ   = (u16*)(ws + 147456000);   // dt bf16 [8192,2048]
  float* XPART = (float*)(ws + 181010432); // 4 x [8192,96] f32 partials
  float* XDBL  = (float*)(ws + 193593344); // [8192,96] f32
  u16*   DTRAW = (u16*)(ws + 196739072);   // [8192,64] bf16
  float* SDT   = (float*)(ws + 196739072); // scan sum_dt [4][32][2048] f32 (reuses DTRAW)
  u16*   F1    = ZB;                       // ffn hidden bf16 [8192,4096]
  float* X2    = (float*)d_out;            // residual stream lives in d_out

  cast_w<<<14656, 256, 0, stream>>>(INW, XPW, DTW, OUTW, W1, W2, WB);
  ln_bf16<<<8192, 256, 0, stream>>>(X, LN1G, LN1B, H1);
  // in_proj: [8192,1024] x [4096,1024]^T -> xi bf16 | z bf16
  gemm_bt<0><<<dim3(32,64,1), 256, 0, stream>>>(H1, bIN, 8192, 4096, 1024, 4096,
                                                nullptr, nullptr, nullptr, ZB, XIPRE);
  conv_silu<<<16384, 256, 0, stream>>>(XIPRE, CONVW, CONVB, XIB);
  // x_proj: [8192,2048] x [96,2048]^T, N padded to 128, K-split 4 -> partials
  gemm_bt<1><<<dim3(1,64,4), 256, 0, stream>>>(XIB, bXP, 8192, 128, 2048, 96,
                                               XPART, nullptr, nullptr, nullptr, nullptr);
  xred<<<3072, 256, 0, stream>>>(XPART, XDBL, DTRAW);
  // dt_proj: [8192,64] x [2048,64]^T, + bias, softplus -> bf16
  gemm_bt<2><<<dim3(16,64,1), 256, 0, stream>>>(DTRAW, bDT, 8192, 2048, 64, 2048,
                                                nullptr, DTBIA, nullptr, DTQ, nullptr);
  // chunked scan: A (local), B (chunk fixup, in-place), C (final + gate)
  scan_a<<<dim3(8,4,32), 256, 0, stream>>>(DTQ, XIB, XDBL, ALOG, HEND, SDT);
  scan_b<<<512, 256, 0, stream>>>(HEND, SDT, ALOG);
  scan_c<<<dim3(8,4,32), 256, 0, stream>>>(DTQ, XIB, ZB, XDBL, ALOG, DP, HEND, YG);
  // out_proj + residual(x) -> X2 (= d_out region)
  gemm_bt<3><<<dim3(8,64,1), 256, 0, stream>>>(YG, bOUT, 8192, 1024, 2048, 1024,
                                               X2, nullptr, X, nullptr, nullptr);
  ln_bf16<<<8192, 256, 0, stream>>>(X2, LN2G, LN2B, H1);
  // ffn1 + bias + relu -> bf16
  gemm_bt<4><<<dim3(32,64,1), 256, 0, stream>>>(H1, bW1, 8192, 4096, 1024, 4096,
                                                nullptr, B1, nullptr, F1, nullptr);
  // ffn2 + bias + residual(X2) -> d_out (F0==C1, same-thread RMW)
  gemm_bt<5><<<dim3(8,64,1), 256, 0, stream>>>(F1, bW2, 8192, 1024, 4096, 1024,
                                               (float*)d_out, B2, X2, nullptr, nullptr);
}

// Round 6
// 786.914 us; speedup vs baseline: 1.5466x; 1.0163x over previous
//
#include <hip/hip_runtime.h>

using u16 = unsigned short;
using u32 = unsigned int;

typedef short s16x8 __attribute__((ext_vector_type(8)));
typedef float f32x4 __attribute__((ext_vector_type(4)));

#define DEV static __device__ __forceinline__
#define AS1 __attribute__((address_space(1)))
#define AS3 __attribute__((address_space(3)))

DEV u16 f2bf(float f){
  u32 u = __float_as_uint(f);
  return (u16)((u + 0x7fffu + ((u >> 16) & 1u)) >> 16);
}
DEV float bf2f(u16 h){ return __uint_as_float(((u32)h) << 16); }

DEV void gload_lds16(const u16* g, u16* l){
  __builtin_amdgcn_global_load_lds((const AS1 void*)g, (AS3 void*)l, 16, 0, 0);
}

// ------------------------------------------------------------------
// weight cast fp32 -> bf16, 6 segments packed contiguously
// ------------------------------------------------------------------
__global__ __launch_bounds__(256) void cast_w(
    const float* __restrict__ s0, const float* __restrict__ s1,
    const float* __restrict__ s2, const float* __restrict__ s3,
    const float* __restrict__ s4, const float* __restrict__ s5,
    u16* __restrict__ dst)
{
  size_t base = ((size_t)blockIdx.x * 256 + threadIdx.x) * 4;
  if (base >= 15007744u) return;
  const float* src; size_t off;
  if      (base <  4194304u){ src=s0; off=base;           }
  else if (base <  4390912u){ src=s1; off=base- 4194304u; }
  else if (base <  4521984u){ src=s2; off=base- 4390912u; }
  else if (base <  6619136u){ src=s3; off=base- 4521984u; }
  else if (base < 10813440u){ src=s4; off=base- 6619136u; }
  else                      { src=s5; off=base-10813440u; }
  float4 v = *(const float4*)(src + off);
  *(ushort4*)(dst + base) = make_ushort4(f2bf(v.x), f2bf(v.y), f2bf(v.z), f2bf(v.w));
}

// ------------------------------------------------------------------
// layernorm over 1024, output bf16. one block per row.
// ------------------------------------------------------------------
__global__ __launch_bounds__(256) void ln_bf16(
    const float* __restrict__ x, const float* __restrict__ g,
    const float* __restrict__ b, u16* __restrict__ o)
{
  int row = blockIdx.x, t = threadIdx.x;
  float4 v = ((const float4*)(x + (size_t)row*1024))[t];
  float s  = v.x+v.y+v.z+v.w;
  float ss = v.x*v.x+v.y*v.y+v.z*v.z+v.w*v.w;
  #pragma unroll
  for (int off=32; off; off>>=1){ s += __shfl_down(s,off); ss += __shfl_down(ss,off); }
  __shared__ float red[8];
  int lane = t & 63, w = t >> 6;
  if (lane==0){ red[w]=s; red[4+w]=ss; }
  __syncthreads();
  float S  = red[0]+red[1]+red[2]+red[3];
  float SS = red[4]+red[5]+red[6]+red[7];
  float mu = S * (1.f/1024.f);
  float var = SS * (1.f/1024.f) - mu*mu;
  float rs = rsqrtf(var + 1e-5f);
  float4 gg = ((const float4*)g)[t], bb = ((const float4*)b)[t];
  ((ushort4*)o)[(size_t)row*256 + t] = make_ushort4(
    f2bf((v.x-mu)*rs*gg.x + bb.x), f2bf((v.y-mu)*rs*gg.y + bb.y),
    f2bf((v.z-mu)*rs*gg.z + bb.z), f2bf((v.w-mu)*rs*gg.w + bb.w));
}

// ------------------------------------------------------------------
// causal depthwise conv (D_CONV=4) + bias + silu, bf16 in -> bf16 out
// ------------------------------------------------------------------
__global__ __launch_bounds__(256) void conv_silu(
    const u16* __restrict__ xi, const float* __restrict__ cw,
    const float* __restrict__ cb, u16* __restrict__ ob)
{
  int idx = blockIdx.x*256 + threadIdx.x;   // 4,194,304 threads
  int d4 = (idx & 511) << 2;
  int l  = (idx >> 9) & 2047;
  int b  = idx >> 20;
  float4 w0 = ((const float4*)cw)[d4+0];
  float4 w1 = ((const float4*)cw)[d4+1];
  float4 w2 = ((const float4*)cw)[d4+2];
  float4 w3 = ((const float4*)cw)[d4+3];
  float4 bb = *(const float4*)(cb + d4);
  float a0=bb.x, a1=bb.y, a2=bb.z, a3=bb.w;
  size_t rowbase = ((size_t)b*2048 + l)*2048 + d4;
  #pragma unroll
  for (int j=0;j<4;j++){
    int ls = l - 3 + j;
    if (ls >= 0){
      ushort4 xv = *(const ushort4*)(xi + rowbase + (size_t)(j-3)*2048);
      a0 += (&w0.x)[j]*bf2f(xv.x);
      a1 += (&w1.x)[j]*bf2f(xv.y);
      a2 += (&w2.x)[j]*bf2f(xv.z);
      a3 += (&w3.x)[j]*bf2f(xv.w);
    }
  }
  ushort4 o;
  o.x = f2bf(a0/(1.f+__expf(-a0)));
  o.y = f2bf(a1/(1.f+__expf(-a1)));
  o.z = f2bf(a2/(1.f+__expf(-a2)));
  o.w = f2bf(a3/(1.f+__expf(-a3)));
  *(ushort4*)(ob + rowbase) = o;
}

// ------------------------------------------------------------------
// reduce 4 K-split partials of x_dbl [8192,96]; also emit dt_raw bf16
// ------------------------------------------------------------------
__global__ __launch_bounds__(256) void xred(
    const float* __restrict__ xp, float* __restrict__ xd, u16* __restrict__ dr)
{
  int i = blockIdx.x*256 + threadIdx.x;   // 786432
  float v = xp[i] + xp[786432 + i] + xp[2*786432 + i] + xp[3*786432 + i];
  xd[i] = v;
  int row = i / 96, col = i - row*96;
  if (col < 64) dr[(size_t)row*64 + col] = f2bf(v);
}

// ==================================================================
// Chunked SSM scan (L=2048 -> 32 chunks of 64). Linear recurrence:
// cross-chunk propagator = exp(A * sum(dt)).
// ==================================================================
__global__ __launch_bounds__(256) void scan_a(
    const u16* __restrict__ dtq, const u16* __restrict__ u,
    const float* __restrict__ xdbl, const float* __restrict__ alog,
    float* __restrict__ hend, float* __restrict__ sdt)
{
  int d = blockIdx.x*256 + threadIdx.x;
  int b = blockIdx.y, s = blockIdx.z, l0 = s*64;
  __shared__ float sB[64][16];
  for (int i = threadIdx.x; i < 1024; i += 256){
    int row = i >> 4, c = i & 15;
    sB[row][c] = xdbl[((size_t)(b*2048 + l0 + row))*96 + 64 + c];
  }
  float afn[16];
  #pragma unroll
  for (int n=0;n<16;n++) afn[n] = -__expf(alog[d*16+n]);
  __syncthreads();
  float h[16];
  #pragma unroll
  for (int n=0;n<16;n++) h[n] = 0.f;
  float sum_dt = 0.f;
  size_t base = ((size_t)b*2048 + l0)*2048 + d;
  for (int t=0;t<64;t++){
    float dtv = bf2f(dtq[base]);
    float uv  = bf2f(u[base]);
    sum_dt += dtv;
    float dtu = dtv*uv;
    #pragma unroll
    for (int n=0;n<16;n++)
      h[n] = __expf(dtv*afn[n])*h[n] + dtu*sB[t][n];
    base += 2048;
  }
  sdt[(b*32+s)*2048 + d] = sum_dt;
  size_t hb = ((size_t)(b*32+s)*16)*2048 + d;
  #pragma unroll
  for (int n=0;n<16;n++) hend[hb + (size_t)n*2048] = h[n];
}

__global__ __launch_bounds__(256) void scan_b(
    float* __restrict__ hend, const float* __restrict__ sdt,
    const float* __restrict__ alog)
{
  int g = blockIdx.x*256 + threadIdx.x;  // 131072
  int d = g & 2047, n = (g >> 11) & 15, b = g >> 15;
  float An = -__expf(alog[d*16+n]);
  float h = 0.f;
  for (int s=0;s<32;s++){
    size_t hi = ((size_t)((b*32+s)*16) + n)*2048 + d;
    float he = hend[hi];
    hend[hi] = h;
    h = he + h*__expf(An * sdt[(b*32+s)*2048 + d]);
  }
}

__global__ __launch_bounds__(256) void scan_c(
    const u16* __restrict__ dtq, const u16* __restrict__ u,
    const u16* __restrict__ zb, const float* __restrict__ xdbl,
    const float* __restrict__ alog, const float* __restrict__ dp,
    const float* __restrict__ hstart, u16* __restrict__ yg)
{
  int d = blockIdx.x*256 + threadIdx.x;
  int b = blockIdx.y, s = blockIdx.z, l0 = s*64;
  __shared__ float sB[64][16], sC[64][16];
  for (int i = threadIdx.x; i < 1024; i += 256){
    int row = i >> 4, c = i & 15;
    size_t xb = ((size_t)(b*2048 + l0 + row))*96 + 64;
    sB[row][c] = xdbl[xb + c];
    sC[row][c] = xdbl[xb + 16 + c];
  }
  float afn[16];
  #pragma unroll
  for (int n=0;n<16;n++) afn[n] = -__expf(alog[d*16+n]);
  __syncthreads();
  float h[16];
  size_t hb = ((size_t)((b*32+s)*16))*2048 + d;
  #pragma unroll
  for (int n=0;n<16;n++) h[n] = hstart[hb + (size_t)n*2048];
  float Dpd = dp[d];
  size_t base = ((size_t)b*2048 + l0)*2048 + d;
  for (int t=0;t<64;t++){
    float dtv = bf2f(dtq[base]);
    float uv  = bf2f(u[base]);
    float dtu = dtv*uv;
    float y = 0.f;
    #pragma unroll
    for (int n=0;n<16;n++){
      h[n] = __expf(dtv*afn[n])*h[n] + dtu*sB[t][n];
      y += h[n]*sC[t][n];
    }
    float zv = bf2f(zb[base]);
    float yv = (y + Dpd*uv) * (zv / (1.f + __expf(-zv)));
    yg[base] = f2bf(yv);
    base += 2048;
  }
}

// ==================================================================
// 256x256-tile bf16 GEMM, BK=64, 8 waves (2Mx4N), double-buffered
// 2-phase pipeline (T3 minimum recipe): stage(t+1) || compute(t),
// one __syncthreads() per K-tile. XCD-swizzled 1D grid.
// EPI: 0 = split xi|z bf16 (N=4096), 4 = bias+relu -> bf16
// ==================================================================
DEV void stage256(const u16* __restrict__ A, const u16* __restrict__ W,
                  int K, int bm, int bn, int kt,
                  u16* sA, u16* sB, int w, int lane)
{
  int rlo = lane >> 3, c8 = (lane & 7) * 8;
  #pragma unroll
  for (int j=0;j<4;j++){
    int chunk = w*4 + j;
    int row = chunk*8 + rlo;
    gload_lds16(A + (size_t)(bm+row)*K + kt + c8, sA + chunk*512 + lane*8);
    gload_lds16(W + (size_t)(bn+row)*K + kt + c8, sB + chunk*512 + lane*8);
  }
}

template<int EPI>
__global__ __launch_bounds__(512,2) void gemm256(
    const u16* __restrict__ A, const u16* __restrict__ W,
    int M, int N, int K,
    const float* __restrict__ C0, u16* __restrict__ OB, u16* __restrict__ OB2)
{
  __shared__ __attribute__((aligned(16))) u16 sA[2][256*64];
  __shared__ __attribute__((aligned(16))) u16 sB[2][256*64];
  const int tid = threadIdx.x, lane = tid & 63, w = tid >> 6;
  const int wr = w >> 2, wc = w & 3;
  // XCD-aware swizzle (grid divisible by 8)
  const int nbx = N >> 8;
  const int nwg = (int)gridDim.x;
  const int cpx = nwg >> 3;
  const int bid = (int)blockIdx.x;
  const int swz = (bid & 7)*cpx + (bid >> 3);
  const int bm = (swz / nbx) * 256, bn = (swz % nbx) * 256;

  f32x4 acc[8][4];
  #pragma unroll
  for (int m=0;m<8;m++)
    #pragma unroll
    for (int n=0;n<4;n++) acc[m][n] = (f32x4){0.f,0.f,0.f,0.f};

  const int NT = K >> 6;
  stage256(A, W, K, bm, bn, 0, sA[0], sB[0], w, lane);
  __syncthreads();
  int cur = 0;
  const int frow = lane & 15, ksel = lane >> 4;
  for (int t=0; t<NT; ++t){
    if (t+1 < NT)
      stage256(A, W, K, bm, bn, (t+1)<<6, sA[cur^1], sB[cur^1], w, lane);
    const u16* a_ = sA[cur];
    const u16* b_ = sB[cur];
    #pragma unroll
    for (int qm=0;qm<2;qm++){
      s16x8 af[4][2];
      #pragma unroll
      for (int m=0;m<4;m++)
        #pragma unroll
        for (int ks=0;ks<2;ks++)
          af[m][ks] = *(const s16x8*)&a_[(wr*128 + qm*64 + m*16 + frow)*64 + ks*32 + ksel*8];
      #pragma unroll
      for (int qn=0;qn<2;qn++){
        s16x8 bfr[2][2];
        #pragma unroll
        for (int n2=0;n2<2;n2++)
          #pragma unroll
          for (int ks=0;ks<2;ks++)
            bfr[n2][ks] = *(const s16x8*)&b_[(wc*64 + qn*32 + n2*16 + frow)*64 + ks*32 + ksel*8];
        #pragma unroll
        for (int m=0;m<4;m++)
          #pragma unroll
          for (int n2=0;n2<2;n2++)
            #pragma unroll
            for (int ks=0;ks<2;ks++)
              acc[qm*4+m][qn*2+n2] = __builtin_amdgcn_mfma_f32_16x16x32_bf16(
                  af[m][ks], bfr[n2][ks], acc[qm*4+m][qn*2+n2], 0, 0, 0);
      }
    }
    __syncthreads();
    cur ^= 1;
  }

  const int crow0 = (lane >> 4) * 4;
  const int ccol  = lane & 15;
  #pragma unroll
  for (int mi=0;mi<8;mi++){
    #pragma unroll
    for (int ni=0;ni<4;ni++){
      #pragma unroll
      for (int j=0;j<4;j++){
        int grow = bm + wr*128 + mi*16 + crow0 + j;
        int gcol = bn + wc*64 + ni*16 + ccol;
        float v = acc[mi][ni][j];
        if constexpr (EPI==0){
          if (gcol < 2048) OB2[(size_t)grow*2048 + gcol] = f2bf(v);
          else             OB[(size_t)grow*2048 + (gcol-2048)] = f2bf(v);
        } else {
          v += C0[gcol]; v = fmaxf(v, 0.f);
          OB[(size_t)grow*N + gcol] = f2bf(v);
        }
      }
    }
  }
}

// ------------------------------------------------------------------
// generic bf16 GEMM: out[M,N] = A[M,K] @ W[N,K]^T  (both K-contiguous)
// 128x128 tile, BK=32. XCD-swizzled (x,y) grid (product divisible by 8).
// ------------------------------------------------------------------
template<int EPI>
__global__ __launch_bounds__(256) void gemm_bt(
    const u16* __restrict__ A, const u16* __restrict__ W,
    int M, int N, int K, int Nreal,
    float* __restrict__ F0, const float* __restrict__ C0,
    const float* __restrict__ C1, u16* __restrict__ OB, u16* __restrict__ OB2)
{
  __shared__ __attribute__((aligned(16))) u16 sA[128*32];
  __shared__ __attribute__((aligned(16))) u16 sB[128*32];
  const int tid  = threadIdx.x;
  const int lane = tid & 63;
  const int wid  = tid >> 6;
  const int wr = wid >> 1, wc = wid & 1;
  // XCD swizzle over linearized (x,y)
  const int nbx = (int)gridDim.x;
  const int nwg = nbx * (int)gridDim.y;
  const int cpx = nwg >> 3;
  const int bid = (int)blockIdx.y * nbx + (int)blockIdx.x;
  const int swz = (bid & 7)*cpx + (bid >> 3);
  const int bm = (swz / nbx) * 128, bn = (swz % nbx) * 128;

  const int kchunk = K / (int)gridDim.z;
  const int k0 = (int)blockIdx.z * kchunk, k1 = k0 + kchunk;

  f32x4 acc[4][4];
  #pragma unroll
  for (int m=0;m<4;m++)
    #pragma unroll
    for (int nn=0;nn<4;nn++) acc[m][nn] = (f32x4){0.f,0.f,0.f,0.f};

  const int c0 = tid,        r0a = c0 >> 2, cc0 = c0 & 3;
  const int c1 = tid + 256,  r1a = c1 >> 2, cc1 = c1 & 3;
  int wrow0 = bn + r0a; if (wrow0 > Nreal-1) wrow0 = Nreal-1;
  int wrow1 = bn + r1a; if (wrow1 > Nreal-1) wrow1 = Nreal-1;

  const int frow = lane & 15;
  const int ksel = lane >> 4;

  for (int kt = k0; kt < k1; kt += 32){
    gload_lds16(A + (size_t)(bm + r0a)*K + kt + cc0*8, &sA[c0*8]);
    gload_lds16(A + (size_t)(bm + r1a)*K + kt + cc1*8, &sA[c1*8]);
    gload_lds16(W + (size_t)wrow0*K + kt + cc0*8, &sB[c0*8]);
    gload_lds16(W + (size_t)wrow1*K + kt + cc1*8, &sB[c1*8]);
    __syncthreads();
    s16x8 af[4], bfr[4];
    #pragma unroll
    for (int m=0;m<4;m++)
      af[m] = *(const s16x8*)&sA[(wr*64 + m*16 + frow)*32 + ksel*8];
    #pragma unroll
    for (int nn=0;nn<4;nn++)
      bfr[nn] = *(const s16x8*)&sB[(wc*64 + nn*16 + frow)*32 + ksel*8];
    #pragma unroll
    for (int m=0;m<4;m++)
      #pragma unroll
      for (int nn=0;nn<4;nn++)
        acc[m][nn] = __builtin_amdgcn_mfma_f32_16x16x32_bf16(af[m], bfr[nn], acc[m][nn], 0, 0, 0);
    __syncthreads();
  }

  const int crow0 = (lane >> 4) * 4;
  const int ccol  = lane & 15;
  #pragma unroll
  for (int m=0;m<4;m++){
    #pragma unroll
    for (int nn=0;nn<4;nn++){
      #pragma unroll
      for (int j=0;j<4;j++){
        int grow = bm + wr*64 + m*16 + crow0 + j;
        int gcol = bn + wc*64 + nn*16 + ccol;
        float v = acc[m][nn][j];
        if constexpr (EPI==0){            // split: xi bf16 | z bf16
          if (gcol < 2048) OB2[(size_t)grow*2048 + gcol] = f2bf(v);
          else             OB[(size_t)grow*2048 + (gcol-2048)] = f2bf(v);
        } else if constexpr (EPI==1){     // K-split partial slice
          if (gcol < Nreal)
            F0[((size_t)blockIdx.z*M + grow)*Nreal + gcol] = v;
        } else if constexpr (EPI==2){     // softplus(v + bias) -> bf16
          v += C0[gcol];
          v = (v > 20.f) ? v : log1pf(__expf(v));
          OB[(size_t)grow*N + gcol] = f2bf(v);
        } else if constexpr (EPI==3){     // + residual -> f32
          F0[(size_t)grow*N + gcol] = v + C1[(size_t)grow*N + gcol];
        } else if constexpr (EPI==4){     // bias + relu -> bf16
          v += C0[gcol]; v = fmaxf(v, 0.f);
          OB[(size_t)grow*N + gcol] = f2bf(v);
        } else {                          // 5: bias + residual -> f32
          F0[(size_t)grow*N + gcol] = v + C0[gcol] + C1[(size_t)grow*N + gcol];
        }
      }
    }
  }
}

// ------------------------------------------------------------------
extern "C" void kernel_launch(void* const* d_in, const int* in_sizes, int n_in,
                              void* d_out, int out_size, void* d_ws, size_t ws_size,
                              hipStream_t stream)
{
  const float* X    = (const float*)d_in[0];
  const float* LN1G = (const float*)d_in[1];
  const float* LN1B = (const float*)d_in[2];
  const float* LN2G = (const float*)d_in[3];
  const float* LN2B = (const float*)d_in[4];
  const float* INW  = (const float*)d_in[5];
  const float* CONVW= (const float*)d_in[6];
  const float* CONVB= (const float*)d_in[7];
  const float* XPW  = (const float*)d_in[8];
  const float* DTW  = (const float*)d_in[9];
  const float* DTBIA= (const float*)d_in[10];
  const float* ALOG = (const float*)d_in[11];
  const float* DP   = (const float*)d_in[12];
  const float* OUTW = (const float*)d_in[13];
  const float* W1   = (const float*)d_in[14];
  const float* B1   = (const float*)d_in[15];
  const float* W2   = (const float*)d_in[16];
  const float* B2   = (const float*)d_in[17];

  char* ws = (char*)d_ws;
  u16* WB   = (u16*)ws;
  u16* bIN  = WB;              // [4096,1024]
  u16* bXP  = WB + 4194304;    // [96,2048]
  u16* bDT  = WB + 4390912;    // [2048,64]
  u16* bOUT = WB + 4521984;    // [1024,2048]
  u16* bW1  = WB + 6619136;    // [4096,1024]
  u16* bW2  = WB + 10813440;   // [1024,4096]
  u16*   H1    = (u16*)(ws + 30015488);    // ln out bf16 (h1, later h2)
  float* HEND  = (float*)(ws + 30015488);  // scan h_end/h_start (reuses H1)
  u16*   ZB    = (u16*)(ws + 46792704);    // z bf16 [8192,2048]
  u16*   XIPRE = (u16*)(ws + 80347136);    // xi pre-conv bf16; later YG
  u16*   YG    = XIPRE;
  u16*   XIB   = (u16*)(ws + 113901568);   // u = silu(conv) bf16
  u16*   DTQ   = (u16*)(ws + 147456000);   // dt bf16 [8192,2048]
  float* XPART = (float*)(ws + 181010432); // 4 x [8192,96] f32 partials
  float* XDBL  = (float*)(ws + 193593344); // [8192,96] f32
  u16*   DTRAW = (u16*)(ws + 196739072);   // [8192,64] bf16
  float* SDT   = (float*)(ws + 196739072); // scan sum_dt (reuses DTRAW)
  u16*   F1    = ZB;                       // ffn hidden bf16 [8192,4096]
  float* X2    = (float*)d_out;            // residual stream lives in d_out

  cast_w<<<14656, 256, 0, stream>>>(INW, XPW, DTW, OUTW, W1, W2, WB);
  ln_bf16<<<8192, 256, 0, stream>>>(X, LN1G, LN1B, H1);
  // in_proj: [8192,1024] x [4096,1024]^T -> xi bf16 | z bf16   (256^2 2-phase)
  gemm256<0><<<512, 512, 0, stream>>>(H1, bIN, 8192, 4096, 1024,
                                      nullptr, ZB, XIPRE);
  conv_silu<<<16384, 256, 0, stream>>>(XIPRE, CONVW, CONVB, XIB);
  // x_proj: [8192,2048] x [96,2048]^T, N padded to 128, K-split 4 -> partials
  gemm_bt<1><<<dim3(1,64,4), 256, 0, stream>>>(XIB, bXP, 8192, 128, 2048, 96,
                                               XPART, nullptr, nullptr, nullptr, nullptr);
  xred<<<3072, 256, 0, stream>>>(XPART, XDBL, DTRAW);
  // dt_proj: [8192,64] x [2048,64]^T, + bias, softplus -> bf16
  gemm_bt<2><<<dim3(16,64,1), 256, 0, stream>>>(DTRAW, bDT, 8192, 2048, 64, 2048,
                                                nullptr, DTBIA, nullptr, DTQ, nullptr);
  // chunked scan: A (local), B (chunk fixup, in-place), C (final + gate)
  scan_a<<<dim3(8,4,32), 256, 0, stream>>>(DTQ, XIB, XDBL, ALOG, HEND, SDT);
  scan_b<<<512, 256, 0, stream>>>(HEND, SDT, ALOG);
  scan_c<<<dim3(8,4,32), 256, 0, stream>>>(DTQ, XIB, ZB, XDBL, ALOG, DP, HEND, YG);
  // out_proj + residual(x) -> X2 (= d_out region)
  gemm_bt<3><<<dim3(8,64,1), 256, 0, stream>>>(YG, bOUT, 8192, 1024, 2048, 1024,
                                               X2, nullptr, X, nullptr, nullptr);
  ln_bf16<<<8192, 256, 0, stream>>>(X2, LN2G, LN2B, H1);
  // ffn1 + bias + relu -> bf16   (256^2 2-phase)
  gemm256<4><<<512, 512, 0, stream>>>(H1, bW1, 8192, 4096, 1024,
                                      B1, F1, nullptr);
  // ffn2 + bias + residual(X2) -> d_out (F0==C1, same-thread RMW)
  gemm_bt<5><<<dim3(8,64,1), 256, 0, stream>>>(F1, bW2, 8192, 1024, 4096, 1024,
                                               (float*)d_out, B2, X2, nullptr, nullptr);
}